// Round 9
// baseline (308.766 us; speedup 1.0000x reference)
//
#include <hip/hip_runtime.h>
#include <hip/hip_bf16.h>

// B=4, S=2048, C=1024 attention block, fp32 in/out.
// fp16 MFMA (16x16x32), fp32 accumulate.
//  - proj + scores: 256x256 8-phase v3 (m201 port, third attempt): BK=64,
//    8 waves, 128KiB LDS dbuf, per-phase DOUBLE asm-barriers (2/phase,
//    8/K-tile), m201 stage queue {p0:Bh1(t+1), p2:Ah01(t+2), p3:Bh0(t+2)},
//    counted vmcnt(6) once per K-tile (3 half-tiles in flight), lgkm0+
//    sched_barrier(0) brackets around each 16-MFMA cluster, setprio(1).
//  - attn: proven 128x128 BK=128 kernel (r3/r5 measured)
//  - cvt6 + softmax4: r5 measured versions
// XOR-chunk LDS swizzles throughout (measured 0 bank conflicts).

typedef _Float16 half8 __attribute__((ext_vector_type(8)));
typedef _Float16 half4 __attribute__((ext_vector_type(4)));
typedef float f32x4 __attribute__((ext_vector_type(4)));

#define AS1(p) ((const __attribute__((address_space(1))) void*)(p))
#define AS3(p) ((__attribute__((address_space(3))) void*)(p))
#define MFMA16(a, b, c) __builtin_amdgcn_mfma_f32_16x16x32_f16(a, b, c, 0, 0, 0)
#define BARRIER() asm volatile("s_barrier" ::: "memory")
#define LGKM0() asm volatile("s_waitcnt lgkmcnt(0)" ::: "memory")
#define SGB0() __builtin_amdgcn_sched_barrier(0)

// ---------------- fp32 -> fp16 convert, 6 tensors, ONE launch ---------------
__global__ __launch_bounds__(256) void cvt6_f32_f16(
    const float* __restrict__ q, const float* __restrict__ k,
    const float* __restrict__ v, const float* __restrict__ wq,
    const float* __restrict__ wk, const float* __restrict__ wv,
    _Float16* __restrict__ Xq, _Float16* __restrict__ Wqh) {
    constexpr long XSZ = 8388608, WSZ = 1048576;
    const int b = blockIdx.x;
    const float* s;
    _Float16* d;
    long i;
    if (b < 12288) {
        const int tz = b >> 12;
        s = tz == 0 ? q : tz == 1 ? k : v;
        d = Xq + (long)tz * XSZ;
        i = (long)(b & 4095) * 2048 + threadIdx.x * 8;
    } else {
        const int b2 = b - 12288;
        const int tz = b2 >> 9;
        s = tz == 0 ? wq : tz == 1 ? wk : wv;
        d = Wqh + (long)tz * WSZ;
        i = (long)(b2 & 511) * 2048 + threadIdx.x * 8;
    }
    float4 a = *(const float4*)(s + i);
    float4 c = *(const float4*)(s + i + 4);
    half8 h;
    h[0] = (_Float16)a.x; h[1] = (_Float16)a.y; h[2] = (_Float16)a.z; h[3] = (_Float16)a.w;
    h[4] = (_Float16)c.x; h[5] = (_Float16)c.y; h[6] = (_Float16)c.z; h[7] = (_Float16)c.w;
    *(half8*)(d + i) = h;
}

// ---------------- 256x256 8-phase v3 NT GEMM, BK=64, 512 threads ------------
// 8 waves (2Mx4N), wave tile 128x64, acc[8][4] f32x4.
// Per K-tile t (buf c=t&1), 4 phases, each [reads||stage; BAR; lgkm0; SGB;
// setprio1; 16 MFMA; setprio0; SGB; BAR]:
//  p0: read af[0..3]x2 + bf[0..1]x2 (12); stage Bh1(t+1)->nb; MFMA i0-3,j0-1
//  p1: read af[4..7]x2 (8);                                MFMA i4-7,j0-1
//      (closing BAR => A-region of buf c globally free)
//  p2: read bf[2..3]x2 (4, reuse bfr); stage Ah0+Ah1(t+2)->c; MFMA i0-3,j2-3
//      (closing BAR => B-region free)
//  p3: stage Bh0(t+2)->c; MFMA i4-7,j2-3; vmcnt(6); BAR
// Queue invariant: after tile t's vmcnt(6), in flight = {Ah0,Ah1,Bh0}(t+2)
// (6 loads/wave) and tile t+1 is fully resident. Prologue: tile0 (8 loads) +
// {Ah0,Ah1,Bh0}(1) (6 loads), vmcnt(6). Tail: vmcnt(0) at t=NT-2.
template <int K, int NX_SH, int R, int NYT_SH, bool BIAS, bool F16OUT, bool PROJ3>
__global__ __launch_bounds__(512, 2)
void gemm256(const _Float16* __restrict__ A, const _Float16* __restrict__ Bt,
             const float* __restrict__ b0, const float* __restrict__ b1,
             const float* __restrict__ b2, void* __restrict__ Cout,
             _Float16* __restrict__ VtOut, int N, float scale,
             long sA, long sB, long sC) {
    constexpr int NT = K / 64;
    static_assert(NT >= 3, "prologue needs >=3 K-tiles");
    __shared__ _Float16 sm[2][2][256 * 64] __attribute__((aligned(16)));  // 128 KiB

    const int tid = threadIdx.x;
    const int lane = tid & 63;
    const int wave = tid >> 6;          // 0..7
    const int wm_i = wave >> 2;         // 0..1
    const int wn_i = wave & 3;          // 0..3

    const int lin = blockIdx.x;
    const int g = lin & 7;
    const int sblk = lin >> 3;
    const int xt = sblk & ((1 << NX_SH) - 1);
    const int row_id = g * R + (sblk >> NX_SH);
    const int yt = row_id & ((1 << NYT_SH) - 1);
    const int tz = row_id >> NYT_SH;
    const int m0 = yt * 256;
    const int n0 = xt * 256;

    const float* bias = nullptr;
    if constexpr (PROJ3) {
        A += (long)tz * 8388608;
        Bt += (long)tz * 1048576;
        bias = tz == 0 ? b0 : tz == 1 ? b1 : b2;
    } else {
        A += (long)tz * sA;
        Bt += (long)tz * sB;
    }
    const _Float16* Abase = A + (long)m0 * K;
    const _Float16* Bbase = Bt + (long)n0 * K;

    // staging per-lane constants (8 lanes cover one 128B row)
    const int srow8 = lane >> 3;
    const int sq = ((lane & 7) ^ srow8) << 3;
    // fragment per-lane constants
    const int quad = lane >> 4;
    const int l16 = lane & 15;
    const int e7 = l16 & 7;
    const int ch0 = (quad ^ e7) << 3;        // ks=0 swizzled chunk (halves)
    const int ch1 = ((4 + quad) ^ e7) << 3;  // ks=1
    const int arow = (wm_i * 128 + l16) * 64;
    const int brow = (wn_i * 64 + l16) * 64;

    f32x4 acc[8][4];
#pragma unroll
    for (int i = 0; i < 8; i++)
#pragma unroll
        for (int j = 0; j < 4; j++)
#pragma unroll
            for (int r = 0; r < 4; r++) acc[i][j][r] = 0.0f;

    // stage one half-tile (128 rows x 64 halves = 16KB): 2 loads/thread
    auto STAGE = [&](int bfi, int ab, int half, int kt) {
        const _Float16* gb = ab ? Bbase : Abase;
#pragma unroll
        for (int u = 0; u < 2; ++u) {
            const int c8 = (u << 3) + wave;                 // 8-row chunk 0..15
            const int r = half * 128 + c8 * 8 + srow8;
            __builtin_amdgcn_global_load_lds(
                AS1(gb + (long)r * K + kt * 64 + sq),
                AS3(&sm[bfi][ab][half * 8192 + c8 * 512]), 16, 0, 0);
        }
    };

    // prologue: tile0 fully (8 loads) + tile1 {Ah0,Ah1,Bh0} (6 loads).
    STAGE(0, 0, 0, 0);
    STAGE(0, 0, 1, 0);
    STAGE(0, 1, 0, 0);
    STAGE(0, 1, 1, 0);
    STAGE(1, 0, 0, 1);
    STAGE(1, 0, 1, 1);
    STAGE(1, 1, 0, 1);
    asm volatile("s_waitcnt vmcnt(6)" ::: "memory");  // tile0 resident
    BARRIER();

    half8 af[8][2], bfr[2][2];
#pragma unroll 2
    for (int t = 0; t < NT; ++t) {
        const int c = t & 1;
        const int nb = c ^ 1;
        const _Float16* sAp = sm[c][0];
        const _Float16* sBp = sm[c][1];

        // ============ phase 0 ============
#pragma unroll
        for (int i = 0; i < 4; ++i) {
            af[i][0] = *(const half8*)(sAp + arow + i * 1024 + ch0);
            af[i][1] = *(const half8*)(sAp + arow + i * 1024 + ch1);
        }
#pragma unroll
        for (int j = 0; j < 2; ++j) {
            bfr[j][0] = *(const half8*)(sBp + brow + j * 1024 + ch0);
            bfr[j][1] = *(const half8*)(sBp + brow + j * 1024 + ch1);
        }
        if (t + 1 < NT) STAGE(nb, 1, 1, t + 1);  // Bh1(t+1) -> nb
        asm volatile("s_waitcnt lgkmcnt(8)" ::: "memory");
        BARRIER();
        LGKM0();
        SGB0();
        __builtin_amdgcn_s_setprio(1);
#pragma unroll
        for (int i = 0; i < 4; ++i)
#pragma unroll
            for (int j = 0; j < 2; ++j) {
                acc[i][j] = MFMA16(af[i][0], bfr[j][0], acc[i][j]);
                acc[i][j] = MFMA16(af[i][1], bfr[j][1], acc[i][j]);
            }
        __builtin_amdgcn_s_setprio(0);
        SGB0();
        BARRIER();

        // ============ phase 1 ============
#pragma unroll
        for (int i = 4; i < 8; ++i) {
            af[i][0] = *(const half8*)(sAp + arow + i * 1024 + ch0);
            af[i][1] = *(const half8*)(sAp + arow + i * 1024 + ch1);
        }
        BARRIER();
        LGKM0();
        SGB0();
        __builtin_amdgcn_s_setprio(1);
#pragma unroll
        for (int i = 4; i < 8; ++i)
#pragma unroll
            for (int j = 0; j < 2; ++j) {
                acc[i][j] = MFMA16(af[i][0], bfr[j][0], acc[i][j]);
                acc[i][j] = MFMA16(af[i][1], bfr[j][1], acc[i][j]);
            }
        __builtin_amdgcn_s_setprio(0);
        SGB0();
        BARRIER();  // A-region of buf c globally free

        // ============ phase 2 ============
#pragma unroll
        for (int j = 0; j < 2; ++j) {
            bfr[j][0] = *(const half8*)(sBp + brow + (j + 2) * 1024 + ch0);
            bfr[j][1] = *(const half8*)(sBp + brow + (j + 2) * 1024 + ch1);
        }
        if (t + 2 < NT) {
            STAGE(c, 0, 0, t + 2);  // Ah0(t+2) -> c
            STAGE(c, 0, 1, t + 2);  // Ah1(t+2) -> c
        }
        BARRIER();
        LGKM0();
        SGB0();
        __builtin_amdgcn_s_setprio(1);
#pragma unroll
        for (int i = 0; i < 4; ++i)
#pragma unroll
            for (int j = 0; j < 2; ++j) {
                acc[i][j + 2] = MFMA16(af[i][0], bfr[j][0], acc[i][j + 2]);
                acc[i][j + 2] = MFMA16(af[i][1], bfr[j][1], acc[i][j + 2]);
            }
        __builtin_amdgcn_s_setprio(0);
        SGB0();
        BARRIER();  // B-region of buf c globally free

        // ============ phase 3 ============
        if (t + 2 < NT) STAGE(c, 1, 0, t + 2);  // Bh0(t+2) -> c
        BARRIER();
        SGB0();
        __builtin_amdgcn_s_setprio(1);
#pragma unroll
        for (int i = 4; i < 8; ++i)
#pragma unroll
            for (int j = 0; j < 2; ++j) {
                acc[i][j + 2] = MFMA16(af[i][0], bfr[j][0], acc[i][j + 2]);
                acc[i][j + 2] = MFMA16(af[i][1], bfr[j][1], acc[i][j + 2]);
            }
        __builtin_amdgcn_s_setprio(0);
        SGB0();
        if (t + 2 < NT)
            asm volatile("s_waitcnt vmcnt(6)" ::: "memory");  // t+1 resident
        else if (t + 1 < NT)
            asm volatile("s_waitcnt vmcnt(0)" ::: "memory");  // tail drain
        BARRIER();
    }

    // Epilogue: C/D layout col=lane&15, row=quad*4+reg.
    const bool trout = PROJ3 && tz == 2;
#pragma unroll
    for (int i = 0; i < 8; ++i) {
        const int row = m0 + wm_i * 128 + i * 16 + quad * 4;
#pragma unroll
        for (int j = 0; j < 4; ++j) {
            const int col = n0 + wn_i * 64 + j * 16 + l16;
            const float badd = BIAS ? bias[col] : 0.0f;
            if (trout) {
                const long b = row >> 11;
                const int sl = row & 2047;
                half4 h;
#pragma unroll
                for (int r = 0; r < 4; r++) h[r] = (_Float16)(acc[i][j][r] * scale + badd);
                *(half4*)(VtOut + b * 2097152 + (long)col * 2048 + sl) = h;
            } else if constexpr (PROJ3) {
                _Float16* o = (_Float16*)Cout + (long)tz * 8388608;
#pragma unroll
                for (int r = 0; r < 4; r++)
                    o[(long)(row + r) * N + col] = (_Float16)(acc[i][j][r] * scale + badd);
            } else {
#pragma unroll
                for (int r = 0; r < 4; r++) {
                    float v = acc[i][j][r] * scale + badd;
                    if constexpr (F16OUT)
                        ((_Float16*)Cout + (long)tz * sC)[(long)(row + r) * N + col] = (_Float16)v;
                    else
                        ((float*)Cout + (long)tz * sC)[(long)(row + r) * N + col] = v;
                }
            }
        }
    }
}

// ---------------- NT GEMM, 128x128 tile, BK=128 (attn only, r3/r5) ----------
template <int K, int NX_SH, int R, int NYT_SH, bool F16OUT>
__global__ __launch_bounds__(256, 2)
void gemm_nt(const _Float16* __restrict__ A, const _Float16* __restrict__ Bt,
             void* __restrict__ Cout, int N, float scale,
             long sA, long sB, long sC) {
    __shared__ _Float16 Asm[128 * 128] __attribute__((aligned(16)));
    __shared__ _Float16 Bsm[128 * 128] __attribute__((aligned(16)));
    const int tid = threadIdx.x;
    const int lane = tid & 63;
    const int wave = tid >> 6;

    const int lin = blockIdx.x;
    const int g = lin & 7;
    const int s = lin >> 3;
    const int xt = s & ((1 << NX_SH) - 1);
    const int row_id = g * R + (s >> NX_SH);
    const int yt = row_id & ((1 << NYT_SH) - 1);
    const int tz = row_id >> NYT_SH;     // batch id
    const int m0 = yt * 128;
    const int n0 = xt * 128;

    A += (long)tz * sA;
    Bt += (long)tz * sB;

    const int rin = lane >> 4;
    const int pch = lane & 15;
    const int quad = lane >> 4;
    const int l16 = lane & 15;
    const int wm = (wave >> 1) << 6;
    const int wn = (wave & 1) << 6;
    const int fa_base = (wm + l16) * 128;
    const int fb_base = (wn + l16) * 128;
    int ch[4];
#pragma unroll
    for (int ks = 0; ks < 4; ++ks) ch[ks] = (((ks * 4 + quad) ^ l16) << 3);

    f32x4 acc[4][4];
#pragma unroll
    for (int i = 0; i < 4; i++)
#pragma unroll
        for (int j = 0; j < 4; j++)
#pragma unroll
            for (int r = 0; r < 4; r++) acc[i][j][r] = 0.0f;

    const _Float16* Abase = A + (long)m0 * K;
    const _Float16* Bbase = Bt + (long)n0 * K;

    for (int k0 = 0; k0 < K; k0 += 128) {
        __syncthreads();
#pragma unroll
        for (int u = 0; u < 16; ++u) {
            const int t = wave + u * 4;            // slab 0..63 (A:0-31, B:32-63)
            const int sl = t & 31;
            const int r = sl * 4 + rin;            // row 0..127
            const int lq = (pch ^ (((sl & 3) << 2) + rin)) << 3;  // halves
            if (t < 32) {
                __builtin_amdgcn_global_load_lds(
                    AS1(Abase + (long)r * K + k0 + lq),
                    AS3(Asm + sl * 512), 16, 0, 0);
            } else {
                __builtin_amdgcn_global_load_lds(
                    AS1(Bbase + (long)r * K + k0 + lq),
                    AS3(Bsm + sl * 512), 16, 0, 0);
            }
        }
        __syncthreads();

#pragma unroll
        for (int ks = 0; ks < 4; ++ks) {
            half8 af[4], bf[4];
#pragma unroll
            for (int i = 0; i < 4; i++) af[i] = *(const half8*)(Asm + fa_base + i * 2048 + ch[ks]);
#pragma unroll
            for (int j = 0; j < 4; j++) bf[j] = *(const half8*)(Bsm + fb_base + j * 2048 + ch[ks]);
#pragma unroll
            for (int i = 0; i < 4; i++)
#pragma unroll
                for (int j = 0; j < 4; j++)
                    acc[i][j] = MFMA16(af[i], bf[j], acc[i][j]);
        }
    }

#pragma unroll
    for (int i = 0; i < 4; i++) {
        const int row = m0 + wm + i * 16 + quad * 4;
#pragma unroll
        for (int j = 0; j < 4; j++) {
            const int col = n0 + wn + j * 16 + l16;
#pragma unroll
            for (int r = 0; r < 4; r++) {
                float v = acc[i][j][r] * scale;
                if constexpr (F16OUT)
                    ((_Float16*)Cout + (long)tz * sC)[(long)(row + r) * N + col] = (_Float16)v;
                else
                    ((float*)Cout + (long)tz * sC)[(long)(row + r) * N + col] = v;
            }
        }
    }
}

// ---------------- row softmax: 4 rows/block, 1 row/wave, no barriers --------
__global__ __launch_bounds__(256) void softmax4_f16(const _Float16* __restrict__ S,
                                                    _Float16* __restrict__ P) {
    const int wave = threadIdx.x >> 6;
    const int lane = threadIdx.x & 63;
    const long row = (long)blockIdx.x * 4 + wave;
    const _Float16* src = S + row * 2048;
    _Float16* dst = P + row * 2048;

    half8 h[4];
#pragma unroll
    for (int u = 0; u < 4; u++) h[u] = ((const half8*)src)[lane + 64 * u];
    float v[32];
#pragma unroll
    for (int u = 0; u < 4; u++)
#pragma unroll
        for (int j = 0; j < 8; j++) v[u * 8 + j] = (float)h[u][j];

    float m = v[0];
#pragma unroll
    for (int e = 1; e < 32; e++) m = fmaxf(m, v[e]);
#pragma unroll
    for (int off = 32; off > 0; off >>= 1) m = fmaxf(m, __shfl_xor(m, off, 64));

    float sum = 0.0f;
#pragma unroll
    for (int e = 0; e < 32; e++) { v[e] = __expf(v[e] - m); sum += v[e]; }
#pragma unroll
    for (int off = 32; off > 0; off >>= 1) sum += __shfl_xor(sum, off, 64);
    const float inv = 1.0f / sum;

#pragma unroll
    for (int u = 0; u < 4; u++) {
        half8 o;
#pragma unroll
        for (int j = 0; j < 8; j++) o[j] = (_Float16)(v[u * 8 + j] * inv);
        ((half8*)dst)[lane + 64 * u] = o;
    }
}

// ---------------- launch ----------------------------------------------------
extern "C" void kernel_launch(void* const* d_in, const int* in_sizes, int n_in,
                              void* d_out, int out_size, void* d_ws, size_t ws_size,
                              hipStream_t stream) {
    constexpr int B = 4, S = 2048, C = 1024;
    constexpr long XSZ = (long)B * S * C;   // 8388608

    const float* query = (const float*)d_in[0];
    const float* key   = (const float*)d_in[1];
    const float* value = (const float*)d_in[2];
    const float* Wq = (const float*)d_in[3];
    const float* bq = (const float*)d_in[4];
    const float* Wk = (const float*)d_in[5];
    const float* bk = (const float*)d_in[6];
    const float* Wv = (const float*)d_in[7];
    const float* bv = (const float*)d_in[8];
    float* out = (float*)d_out;
    char* ws = (char*)d_ws;

    // Workspace (bytes): [0,50331648) Xq,Xk,Xv fp16 contiguous; region reused
    // for fp16 scores after the projection. [50331648,56623104) Wqh,Wkh,Wvh.
    // [73400320,106954752) Qh,Kh contiguous (reused for attn probs).
    // [106954752,123731968) Vt.
    _Float16* Xq  = (_Float16*)(ws + 0);
    _Float16* Wqh = (_Float16*)(ws + 3 * XSZ * 2);
    _Float16* scores = (_Float16*)(ws + 0);
    _Float16* Qh  = (_Float16*)(ws + 73400320);
    _Float16* attn = (_Float16*)(ws + 73400320);
    _Float16* Vt  = (_Float16*)(ws + 106954752);
    if (ws_size < 123731968) return;

    // 1) convert inputs + weights to fp16 (one launch, contiguous dests)
    cvt6_f32_f16<<<13824, 256, 0, stream>>>(
        query, key, value, Wq, Wk, Wv, Xq, Wqh);

    // 2) merged projections (256² 8-phase v3): per tensor M=8192 (32 yt),
    //    N=1024 (4 xt). row_ids = 96, R = 12, grid = 8*12*4 = 384.
    gemm256<1024, 2, 12, 5, true, true, true><<<384, 512, 0, stream>>>(
        Xq, Wqh, bq, bk, bv, Qh, Vt, C, 1.0f, 0, 0, 0);

    // 3) scores = Qh @ Kh^T / 32 (256² 8-phase v3): 8 yt x 8 xt x 4 batches,
    //    grid 256.
    gemm256<1024, 3, 4, 3, false, true, false><<<256, 512, 0, stream>>>(
        Qh, Qh + XSZ, nullptr, nullptr, nullptr, scores, nullptr, S, 0.03125f,
        (long)S * C, (long)S * C, (long)S * S);

    // 4) row softmax (fp16 in/out), 4 rows/block, no barriers
    softmax4_f16<<<B * S / 4, 256, 0, stream>>>(scores, attn);

    // 5) out = attn @ Vt^T (128² BK=128). 8 x, 16 y, z=4 -> grid 512. fp32.
    gemm_nt<2048, 3, 8, 4, false><<<512, 256, 0, stream>>>(
        attn, Vt, out, C, 1.0f,
        (long)S * S, (long)C * S, (long)S * C);
}

// Round 10
// 299.270 us; speedup vs baseline: 1.0317x; 1.0317x over previous
//
#include <hip/hip_runtime.h>
#include <hip/hip_bf16.h>

// B=4, S=2048, C=1024 attention block, fp32 in/out.
// fp16 MFMA (16x16x32), fp32 accumulate. FINAL best-of-measured composition
// (r5 reproduction; each piece at its best measured value across 10 rounds):
//  - cvt6: merged fp32->fp16 convert, inputs+weights, one dispatch (~28us)
//  - proj: BK=64, 32KB LDS, gload_lds staging (62.3-63.2us measured, 818 TF)
//  - scores/attn: BK=128, 64KB LDS (fewer barrier drains at long K)
//  - softmax4: 1 row/wave, pure shuffle, no LDS/no barriers (~10us, BW floor)
// Rejected by measurement: 256^2 8-phase ports x3 (77/77/93us vs 63), fused
// A-convert reg-staging (175us), exp-scores pipelines (neutral).
// XOR-chunk LDS swizzles throughout (measured 0 bank conflicts).

typedef _Float16 half8 __attribute__((ext_vector_type(8)));
typedef _Float16 half4 __attribute__((ext_vector_type(4)));
typedef float f32x4 __attribute__((ext_vector_type(4)));

#define AS1(p) ((const __attribute__((address_space(1))) void*)(p))
#define AS3(p) ((__attribute__((address_space(3))) void*)(p))
#define MFMA16(a, b, c) __builtin_amdgcn_mfma_f32_16x16x32_f16(a, b, c, 0, 0, 0)

// ---------------- fp32 -> fp16 convert, 6 tensors, ONE launch ---------------
__global__ __launch_bounds__(256) void cvt6_f32_f16(
    const float* __restrict__ q, const float* __restrict__ k,
    const float* __restrict__ v, const float* __restrict__ wq,
    const float* __restrict__ wk, const float* __restrict__ wv,
    _Float16* __restrict__ Xq, _Float16* __restrict__ Wqh) {
    constexpr long XSZ = 8388608, WSZ = 1048576;
    const int b = blockIdx.x;
    const float* s;
    _Float16* d;
    long i;
    if (b < 12288) {
        const int tz = b >> 12;
        s = tz == 0 ? q : tz == 1 ? k : v;
        d = Xq + (long)tz * XSZ;
        i = (long)(b & 4095) * 2048 + threadIdx.x * 8;
    } else {
        const int b2 = b - 12288;
        const int tz = b2 >> 9;
        s = tz == 0 ? wq : tz == 1 ? wk : wv;
        d = Wqh + (long)tz * WSZ;
        i = (long)(b2 & 511) * 2048 + threadIdx.x * 8;
    }
    float4 a = *(const float4*)(s + i);
    float4 c = *(const float4*)(s + i + 4);
    half8 h;
    h[0] = (_Float16)a.x; h[1] = (_Float16)a.y; h[2] = (_Float16)a.z; h[3] = (_Float16)a.w;
    h[4] = (_Float16)c.x; h[5] = (_Float16)c.y; h[6] = (_Float16)c.z; h[7] = (_Float16)c.w;
    *(half8*)(d + i) = h;
}

// ---------------- projection GEMM, 128x128 tile, BK=64 (62.3us measured) ----
// C[m,n] = sum_k A[m,k]*Bt[n,k] + bias[n], Q/K/V in one dispatch, V -> Vt.
// LDS rows = 64 halves (128B = 8 x 16B chunks); chunk q of row r at q^(r&7).
__global__ __launch_bounds__(256, 2)
void gemm_proj(const _Float16* __restrict__ A, const _Float16* __restrict__ Bt,
               const float* __restrict__ b0, const float* __restrict__ b1,
               const float* __restrict__ b2, _Float16* __restrict__ QKout,
               _Float16* __restrict__ VtOut) {
    constexpr int K = 1024;
    __shared__ _Float16 Asm[128 * 64] __attribute__((aligned(16)));
    __shared__ _Float16 Bsm[128 * 64] __attribute__((aligned(16)));
    const int tid = threadIdx.x;
    const int lane = tid & 63;
    const int wave = tid >> 6;

    // grid 1536 = 8 xcd * (R=24 row_ids) * 8 xt; row_id in 0..191
    const int lin = blockIdx.x;
    const int g = lin & 7;
    const int s = lin >> 3;
    const int xt = s & 7;
    const int row_id = g * 24 + (s >> 3);
    const int yt = row_id & 63;
    const int tz = row_id >> 6;          // 0,1,2 = Q,K,V
    const int m0 = yt * 128;
    const int n0 = xt * 128;

    const float* bias = tz == 0 ? b0 : tz == 1 ? b1 : b2;
    const _Float16* Abase = A + (long)tz * 8388608 + (long)m0 * K;
    const _Float16* Bbase = Bt + (long)tz * 1048576 + (long)n0 * K;

    const int srow8 = lane >> 3;
    const int sq = ((lane & 7) ^ srow8) << 3;
    const int quad = lane >> 4;
    const int l16 = lane & 15;
    const int wm = (wave >> 1) << 6;
    const int wn = (wave & 1) << 6;
    const int fa0 = (wm + l16) * 64 + (((0 * 4 + quad) ^ (l16 & 7)) << 3);
    const int fa1 = (wm + l16) * 64 + (((1 * 4 + quad) ^ (l16 & 7)) << 3);
    const int fb0 = (wn + l16) * 64 + (((0 * 4 + quad) ^ (l16 & 7)) << 3);
    const int fb1 = (wn + l16) * 64 + (((1 * 4 + quad) ^ (l16 & 7)) << 3);

    f32x4 acc[4][4];
#pragma unroll
    for (int i = 0; i < 4; i++)
#pragma unroll
        for (int j = 0; j < 4; j++)
#pragma unroll
            for (int r = 0; r < 4; r++) acc[i][j][r] = 0.0f;

    for (int k0 = 0; k0 < K; k0 += 64) {
        __syncthreads();
#pragma unroll
        for (int u = 0; u < 8; ++u) {
            const int t = wave + u * 4;  // slab 0..31 (A:0-15, B:16-31)
            if (t < 16) {
                __builtin_amdgcn_global_load_lds(
                    AS1(Abase + (long)(t * 8 + srow8) * K + k0 + sq),
                    AS3(Asm + t * 512), 16, 0, 0);
            } else {
                __builtin_amdgcn_global_load_lds(
                    AS1(Bbase + (long)((t - 16) * 8 + srow8) * K + k0 + sq),
                    AS3(Bsm + (t - 16) * 512), 16, 0, 0);
            }
        }
        __syncthreads();

#pragma unroll
        for (int ks = 0; ks < 2; ++ks) {
            const int ao = ks ? fa1 : fa0;
            const int bo = ks ? fb1 : fb0;
            half8 af[4], bf[4];
#pragma unroll
            for (int i = 0; i < 4; i++) af[i] = *(const half8*)(Asm + ao + i * 1024);
#pragma unroll
            for (int j = 0; j < 4; j++) bf[j] = *(const half8*)(Bsm + bo + j * 1024);
#pragma unroll
            for (int i = 0; i < 4; i++)
#pragma unroll
                for (int j = 0; j < 4; j++)
                    acc[i][j] = MFMA16(af[i], bf[j], acc[i][j]);
        }
    }

    // Epilogue: C/D layout col=lane&15, row=quad*4+reg.
    const bool trout = (tz == 2);
#pragma unroll
    for (int i = 0; i < 4; i++) {
        const int row = m0 + wm + i * 16 + quad * 4;
#pragma unroll
        for (int j = 0; j < 4; j++) {
            const int col = n0 + wn + j * 16 + l16;
            const float badd = bias[col];
            if (trout) {
                const long b = row >> 11;
                const int sl = row & 2047;
                half4 h;
#pragma unroll
                for (int r = 0; r < 4; r++) h[r] = (_Float16)(acc[i][j][r] + badd);
                *(half4*)(VtOut + b * 2097152 + (long)col * 2048 + sl) = h;
            } else {
                _Float16* o = QKout + (long)tz * 8388608;
#pragma unroll
                for (int r = 0; r < 4; r++)
                    o[(long)(row + r) * 1024 + col] = (_Float16)(acc[i][j][r] + badd);
            }
        }
    }
}

// ---------------- NT GEMM, 128x128 tile, BK=128 (scores + attn) -------------
// LDS rows = 128 halves (256B = 16 x 16B chunks); chunk q of row r at q^(r&15).
template <int K, int NX_SH, int R, int NYT_SH, bool F16OUT>
__global__ __launch_bounds__(256, 2)
void gemm_nt(const _Float16* __restrict__ A, const _Float16* __restrict__ Bt,
             void* __restrict__ Cout, int N, float scale,
             long sA, long sB, long sC) {
    __shared__ _Float16 Asm[128 * 128] __attribute__((aligned(16)));
    __shared__ _Float16 Bsm[128 * 128] __attribute__((aligned(16)));
    const int tid = threadIdx.x;
    const int lane = tid & 63;
    const int wave = tid >> 6;

    const int lin = blockIdx.x;
    const int g = lin & 7;
    const int s = lin >> 3;
    const int xt = s & ((1 << NX_SH) - 1);
    const int row_id = g * R + (s >> NX_SH);
    const int yt = row_id & ((1 << NYT_SH) - 1);
    const int tz = row_id >> NYT_SH;     // batch id
    const int m0 = yt * 128;
    const int n0 = xt * 128;

    A += (long)tz * sA;
    Bt += (long)tz * sB;

    const int rin = lane >> 4;
    const int pch = lane & 15;
    const int quad = lane >> 4;
    const int l16 = lane & 15;
    const int wm = (wave >> 1) << 6;
    const int wn = (wave & 1) << 6;
    const int fa_base = (wm + l16) * 128;
    const int fb_base = (wn + l16) * 128;
    int ch[4];
#pragma unroll
    for (int ks = 0; ks < 4; ++ks) ch[ks] = (((ks * 4 + quad) ^ l16) << 3);

    f32x4 acc[4][4];
#pragma unroll
    for (int i = 0; i < 4; i++)
#pragma unroll
        for (int j = 0; j < 4; j++)
#pragma unroll
            for (int r = 0; r < 4; r++) acc[i][j][r] = 0.0f;

    const _Float16* Abase = A + (long)m0 * K;
    const _Float16* Bbase = Bt + (long)n0 * K;

    for (int k0 = 0; k0 < K; k0 += 128) {
        __syncthreads();
#pragma unroll
        for (int u = 0; u < 16; ++u) {
            const int t = wave + u * 4;            // slab 0..63 (A:0-31, B:32-63)
            const int sl = t & 31;
            const int r = sl * 4 + rin;            // row 0..127
            const int lq = (pch ^ (((sl & 3) << 2) + rin)) << 3;  // halves
            if (t < 32) {
                __builtin_amdgcn_global_load_lds(
                    AS1(Abase + (long)r * K + k0 + lq),
                    AS3(Asm + sl * 512), 16, 0, 0);
            } else {
                __builtin_amdgcn_global_load_lds(
                    AS1(Bbase + (long)r * K + k0 + lq),
                    AS3(Bsm + sl * 512), 16, 0, 0);
            }
        }
        __syncthreads();

#pragma unroll
        for (int ks = 0; ks < 4; ++ks) {
            half8 af[4], bf[4];
#pragma unroll
            for (int i = 0; i < 4; i++) af[i] = *(const half8*)(Asm + fa_base + i * 2048 + ch[ks]);
#pragma unroll
            for (int j = 0; j < 4; j++) bf[j] = *(const half8*)(Bsm + fb_base + j * 2048 + ch[ks]);
#pragma unroll
            for (int i = 0; i < 4; i++)
#pragma unroll
                for (int j = 0; j < 4; j++)
                    acc[i][j] = MFMA16(af[i], bf[j], acc[i][j]);
        }
    }

#pragma unroll
    for (int i = 0; i < 4; i++) {
        const int row = m0 + wm + i * 16 + quad * 4;
#pragma unroll
        for (int j = 0; j < 4; j++) {
            const int col = n0 + wn + j * 16 + l16;
#pragma unroll
            for (int r = 0; r < 4; r++) {
                float v = acc[i][j][r] * scale;
                if constexpr (F16OUT)
                    ((_Float16*)Cout + (long)tz * sC)[(long)(row + r) * N + col] = (_Float16)v;
                else
                    ((float*)Cout + (long)tz * sC)[(long)(row + r) * N + col] = v;
            }
        }
    }
}

// ---------------- row softmax: 4 rows/block, 1 row/wave, no barriers --------
__global__ __launch_bounds__(256) void softmax4_f16(const _Float16* __restrict__ S,
                                                    _Float16* __restrict__ P) {
    const int wave = threadIdx.x >> 6;
    const int lane = threadIdx.x & 63;
    const long row = (long)blockIdx.x * 4 + wave;
    const _Float16* src = S + row * 2048;
    _Float16* dst = P + row * 2048;

    half8 h[4];
#pragma unroll
    for (int u = 0; u < 4; u++) h[u] = ((const half8*)src)[lane + 64 * u];
    float v[32];
#pragma unroll
    for (int u = 0; u < 4; u++)
#pragma unroll
        for (int j = 0; j < 8; j++) v[u * 8 + j] = (float)h[u][j];

    float m = v[0];
#pragma unroll
    for (int e = 1; e < 32; e++) m = fmaxf(m, v[e]);
#pragma unroll
    for (int off = 32; off > 0; off >>= 1) m = fmaxf(m, __shfl_xor(m, off, 64));

    float sum = 0.0f;
#pragma unroll
    for (int e = 0; e < 32; e++) { v[e] = __expf(v[e] - m); sum += v[e]; }
#pragma unroll
    for (int off = 32; off > 0; off >>= 1) sum += __shfl_xor(sum, off, 64);
    const float inv = 1.0f / sum;

#pragma unroll
    for (int u = 0; u < 4; u++) {
        half8 o;
#pragma unroll
        for (int j = 0; j < 8; j++) o[j] = (_Float16)(v[u * 8 + j] * inv);
        ((half8*)dst)[lane + 64 * u] = o;
    }
}

// ---------------- launch ----------------------------------------------------
extern "C" void kernel_launch(void* const* d_in, const int* in_sizes, int n_in,
                              void* d_out, int out_size, void* d_ws, size_t ws_size,
                              hipStream_t stream) {
    constexpr int B = 4, S = 2048, C = 1024;
    constexpr long XSZ = (long)B * S * C;   // 8388608

    const float* query = (const float*)d_in[0];
    const float* key   = (const float*)d_in[1];
    const float* value = (const float*)d_in[2];
    const float* Wq = (const float*)d_in[3];
    const float* bq = (const float*)d_in[4];
    const float* Wk = (const float*)d_in[5];
    const float* bk = (const float*)d_in[6];
    const float* Wv = (const float*)d_in[7];
    const float* bv = (const float*)d_in[8];
    float* out = (float*)d_out;
    char* ws = (char*)d_ws;

    // Workspace (bytes): [0,50331648) Xq,Xk,Xv fp16 contiguous; region reused
    // for fp16 scores after the projection. [50331648,56623104) Wqh,Wkh,Wvh.
    // [73400320,106954752) Qh,Kh contiguous (reused for attn probs).
    // [106954752,123731968) Vt.
    _Float16* Xq  = (_Float16*)(ws + 0);
    _Float16* Wqh = (_Float16*)(ws + 3 * XSZ * 2);
    _Float16* scores = (_Float16*)(ws + 0);
    _Float16* Qh  = (_Float16*)(ws + 73400320);
    _Float16* attn = (_Float16*)(ws + 73400320);
    _Float16* Vt  = (_Float16*)(ws + 106954752);
    if (ws_size < 123731968) return;

    // 1) convert inputs + weights to fp16 (one launch, contiguous dests)
    cvt6_f32_f16<<<13824, 256, 0, stream>>>(
        query, key, value, Wq, Wk, Wv, Xq, Wqh);

    // 2) merged projections (BK=64): per tensor M=8192 (64 y), N=1024 (8 x),
    //    K=1024. row_ids = 192, grid = 1536, R = 24.
    gemm_proj<<<1536, 256, 0, stream>>>(
        Xq, Wqh, bq, bk, bv, Qh, Vt);

    // 3) scores = Qh @ Kh^T / 32, fp16 out (BK=128). 16 x, 16 y, z=4 ->
    //    grid 1024, R=8.
    gemm_nt<1024, 4, 8, 4, true><<<1024, 256, 0, stream>>>(
        Qh, Qh + XSZ, scores, S, 0.03125f,
        (long)S * C, (long)S * C, (long)S * S);

    // 4) row softmax (fp16 in/out), 4 rows/block, no barriers
    softmax4_f16<<<B * S / 4, 256, 0, stream>>>(scores, attn);

    // 5) out = attn @ Vt^T (BK=128). 8 x, 16 y, z=4 -> grid 512. fp32 out.
    gemm_nt<2048, 3, 8, 4, false><<<512, 256, 0, stream>>>(
        attn, Vt, out, C, 1.0f,
        (long)S * S, (long)C * S, (long)S * C);
}